// Round 8
// baseline (165.033 us; speedup 1.0000x reference)
//
#include <hip/hip_runtime.h>
#include <hip/hip_bf16.h>
#include <math.h>

// Sizes fixed by the reference.
#define T_PTS 400
#define D_OUT 10000
#define L12   1200   // len(features1) == len(features2)
#define L3    800    // len(features3)
#define ROW   3200   // concatenated [W1row | W2row | W3row]

// ---------------------------------------------------------------------------
// Kernel 1: build the feature vector from input (T,4) into ws:
//   [0,1200) f1 = [x,y,z], [1200,2400) f2 = jerks, [2400,3200) f3 = mags,
//   [3200,3203) energy
// ---------------------------------------------------------------------------
__global__ __launch_bounds__(512)
void hdc_features_kernel(const float* __restrict__ in, float* __restrict__ feat) {
    __shared__ float red[3][8];
    const int tid = threadIdx.x;          // 0..511
    float ex = 0.f, ey = 0.f, ez = 0.f;

    if (tid < T_PTS) {
        const float4 cur = reinterpret_cast<const float4*>(in)[tid];
        const float x = cur.y, y = cur.z, z = cur.w;
        feat[tid]        = x;
        feat[400 + tid]  = y;
        feat[800 + tid]  = z;
        feat[2400 + tid] = sqrtf(x * x + y * y + z * z);
        ex = x * x; ey = y * y; ez = z * z;

        float jx = 0.f, jy = 0.f, jz = 0.f;
        if (tid > 0) {
            const float4 prev = reinterpret_cast<const float4*>(in)[tid - 1];
            const float dt = cur.x - prev.x;           // t0 offset cancels
            const float inv = 1.0f / dt;
            jx = (x - prev.y) * inv;
            jy = (y - prev.z) * inv;
            jz = (z - prev.w) * inv;
        }
        feat[1200 + tid] = jx;
        feat[1600 + tid] = jy;
        feat[2000 + tid] = jz;
        feat[2800 + tid] = sqrtf(jx * jx + jy * jy + jz * jz);
    }

    #pragma unroll
    for (int off = 32; off; off >>= 1) {
        ex += __shfl_down(ex, off, 64);
        ey += __shfl_down(ey, off, 64);
        ez += __shfl_down(ez, off, 64);
    }
    const int wave = tid >> 6, lane = tid & 63;
    if (lane == 0) { red[0][wave] = ex; red[1][wave] = ey; red[2][wave] = ez; }
    __syncthreads();
    if (tid == 0) {
        float sx = 0.f, sy = 0.f, sz = 0.f;
        #pragma unroll
        for (int w = 0; w < 8; ++w) { sx += red[0][w]; sy += red[1][w]; sz += red[2][w]; }
        const float invT = 1.0f / (float)T_PTS;
        feat[3200] = sx * invT;
        feat[3201] = sy * invT;
        feat[3202] = sz * invT;
    }
}

// Per-row weight load: 12 float4 + 1 float2 covering the concatenated row.
// Boundary steps i=4 (k straddles 1200) and i=9 (k straddles 2400) select the
// source matrix per lane; a float4 never straddles (176 and 96 are mult of 4).
#define LOAD_ROW()                                                            \
    do {                                                                      \
        _Pragma("unroll")                                                     \
        for (int i = 0; i < 12; ++i) {                                        \
            const int k = 256 * i + c0;                                       \
            const float* p;                                                   \
            if (i < 4)       p = w1 + k;                                      \
            else if (i == 4) p = (k < L12) ? (w1 + k) : (w2 + (k - L12));     \
            else if (i < 9)  p = w2 + (k - L12);                              \
            else if (i == 9) p = (k < 2400) ? (w2 + (k - L12))                \
                                            : (w3 + (k - 2400));              \
            else             p = w3 + (k - 2400);                             \
            r[i] = *reinterpret_cast<const float4*>(p);                       \
        }                                                                     \
        rt = *reinterpret_cast<const float2*>(w3 + 672 + 2 * lane);           \
    } while (0)

// ---------------------------------------------------------------------------
// Kernel 2: fused 4-way GEMV + tanh epilogue. 1250 blocks x 128 threads
// (2 waves). Wave g = 2*blockIdx + wave owns rows {g, g+2500, g+5000, g+7500}.
// Latency-bound fix (R7: one 13KB burst per wave lifetime -> ~40% load duty):
//  - features held in REGISTERS (50 VGPR), loaded once, reused for all 4 rows
//    -> no LDS, no barrier, no vmcnt(0) drain;
//  - per row, the NEXT row's 13 loads are issued before the current row's
//    butterfly reduce, so flight overlaps reduce/select (~80% duty);
//  - butterfly (shfl_xor) leaves sums in all lanes; lane r keeps row r, so
//    the 4 rows' tanh epilogues run in parallel in lanes 0..3 (one chain,
//    not four serial lane-0 chains).
// VGPR by construction ~120 (48 s + 48 r + accs/keeps + misc): no spill.
// ---------------------------------------------------------------------------
__global__ __launch_bounds__(128)
void hdc_gemv_kernel(const float* __restrict__ W1, const float* __restrict__ b1,
                     const float* __restrict__ W2, const float* __restrict__ b2,
                     const float* __restrict__ W3, const float* __restrict__ b3,
                     const float* __restrict__ W4, const float* __restrict__ b4,
                     const float* __restrict__ feat, float* __restrict__ out) {
    const int tid = threadIdx.x;
    const int wave = tid >> 6, lane = tid & 63;
    const int g = blockIdx.x * 2 + wave;        // 0..2499
    const int c0 = lane * 4;                    // 0..252

    // ---- Features into registers (L1/L2-cached; same addrs for all waves) --
    float4 s[12];
    #pragma unroll
    for (int i = 0; i < 12; ++i)
        s[i] = *reinterpret_cast<const float4*>(feat + 256 * i + c0);
    const float2 st = *reinterpret_cast<const float2*>(feat + 3072 + 2 * lane);

    const float* __restrict__ w1 = W1 + (size_t)g * L12;
    const float* __restrict__ w2 = W2 + (size_t)g * L12;
    const float* __restrict__ w3 = W3 + (size_t)g * L3;

    float4 r[12];
    float2 rt;
    LOAD_ROW();                                 // row 0 in flight

    float k1 = 0.f, k2 = 0.f, k3 = 0.f;         // lane rr keeps row rr's sums

    for (int rr = 0; rr < 4; ++rr) {
        // ---- consume current row (waitcnt inserted by compiler) ----
        float a1 = 0.f, a2 = 0.f, a3 = 0.f;
        #pragma unroll
        for (int i = 0; i < 12; ++i) {
            const int k = 256 * i + c0;
            const float t = r[i].x * s[i].x + r[i].y * s[i].y +
                            r[i].z * s[i].z + r[i].w * s[i].w;
            if (i < 4)       a1 += t;
            else if (i == 4) { a1 += (k < L12) ? t : 0.f; a2 += (k < L12) ? 0.f : t; }
            else if (i < 9)  a2 += t;
            else if (i == 9) { a2 += (k < 2400) ? t : 0.f; a3 += (k < 2400) ? 0.f : t; }
            else             a3 += t;
        }
        a3 += rt.x * st.x + rt.y * st.y;

        // ---- issue next row's loads before the reduce (overlap flight) ----
        if (rr < 3) {
            w1 += (size_t)2500 * L12;
            w2 += (size_t)2500 * L12;
            w3 += (size_t)2500 * L3;
            LOAD_ROW();
        }

        // ---- butterfly reduce (all lanes get full sums), lane rr keeps ----
        #pragma unroll
        for (int off = 32; off; off >>= 1) {
            a1 += __shfl_xor(a1, off, 64);
            a2 += __shfl_xor(a2, off, 64);
            a3 += __shfl_xor(a3, off, 64);
        }
        if (lane == rr) { k1 = a1; k2 = a2; k3 = a3; }
    }

    // ---- parallel epilogue: lane r handles row g + r*2500 ----
    if (lane < 4) {
        const int d = g + lane * 2500;
        const float e0 = feat[3200], e1 = feat[3201], e2 = feat[3202];
        const float hv1 = tanhf(k1 + b1[d]);
        const float hv2 = tanhf(k2 + b2[d]);
        const float hv3 = tanhf(k3 + b3[d]);
        const float hv4 = tanhf(W4[(size_t)d * 3 + 0] * e0 +
                                W4[(size_t)d * 3 + 1] * e1 +
                                W4[(size_t)d * 3 + 2] * e2 + b4[d]);
        out[d] = tanhf(hv1 * hv4 + hv2 + hv3);
    }
}

extern "C" void kernel_launch(void* const* d_in, const int* in_sizes, int n_in,
                              void* d_out, int out_size, void* d_ws, size_t ws_size,
                              hipStream_t stream) {
    const float* input = (const float*)d_in[0];
    const float* W1 = (const float*)d_in[1];
    const float* b1 = (const float*)d_in[2];
    const float* W2 = (const float*)d_in[3];
    const float* b2 = (const float*)d_in[4];
    const float* W3 = (const float*)d_in[5];
    const float* b3 = (const float*)d_in[6];
    const float* W4 = (const float*)d_in[7];
    const float* b4 = (const float*)d_in[8];
    float* out = (float*)d_out;
    float* feat = (float*)d_ws;

    hdc_features_kernel<<<1, 512, 0, stream>>>(input, feat);
    hdc_gemv_kernel<<<1250, 128, 0, stream>>>(W1, b1, W2, b2, W3, b3,
                                              W4, b4, feat, out);
}

// Round 9
// 164.679 us; speedup vs baseline: 1.0022x; 1.0022x over previous
//
#include <hip/hip_runtime.h>
#include <hip/hip_bf16.h>
#include <math.h>

// Sizes fixed by the reference.
#define T_PTS 400
#define D_OUT 10000
#define L12   1200
#define L3    800

// Workspace layout (floats):
//   [0, 3328)            feature vector (3203 used, padded)
//   [3328, 3328+160000)  partials: partial[row*16 + slot]
#define FEAT_F 3328
#define PART_OFF 3328
#define WS_NEED ((FEAT_F + 16 * D_OUT) * sizeof(float))

// ---------------------------------------------------------------------------
// Kernel 1: build the feature vector from input (T,4) into ws.
// ---------------------------------------------------------------------------
__global__ __launch_bounds__(512)
void hdc_features_kernel(const float* __restrict__ in, float* __restrict__ feat) {
    __shared__ float red[3][8];
    const int tid = threadIdx.x;          // 0..511
    float ex = 0.f, ey = 0.f, ez = 0.f;

    if (tid < T_PTS) {
        const float4 cur = reinterpret_cast<const float4*>(in)[tid];
        const float x = cur.y, y = cur.z, z = cur.w;
        feat[tid]        = x;
        feat[400 + tid]  = y;
        feat[800 + tid]  = z;
        feat[2400 + tid] = sqrtf(x * x + y * y + z * z);
        ex = x * x; ey = y * y; ez = z * z;

        float jx = 0.f, jy = 0.f, jz = 0.f;
        if (tid > 0) {
            const float4 prev = reinterpret_cast<const float4*>(in)[tid - 1];
            const float dt = cur.x - prev.x;           // t0 offset cancels
            const float inv = 1.0f / dt;
            jx = (x - prev.y) * inv;
            jy = (y - prev.z) * inv;
            jz = (z - prev.w) * inv;
        }
        feat[1200 + tid] = jx;
        feat[1600 + tid] = jy;
        feat[2000 + tid] = jz;
        feat[2800 + tid] = sqrtf(jx * jx + jy * jy + jz * jz);
    }

    #pragma unroll
    for (int off = 32; off; off >>= 1) {
        ex += __shfl_down(ex, off, 64);
        ey += __shfl_down(ey, off, 64);
        ez += __shfl_down(ez, off, 64);
    }
    const int wave = tid >> 6, lane = tid & 63;
    if (lane == 0) { red[0][wave] = ex; red[1][wave] = ey; red[2][wave] = ez; }
    __syncthreads();
    if (tid == 0) {
        float sx = 0.f, sy = 0.f, sz = 0.f;
        #pragma unroll
        for (int w = 0; w < 8; ++w) { sx += red[0][w]; sy += red[1][w]; sz += red[2][w]; }
        const float invT = 1.0f / (float)T_PTS;
        feat[3200] = sx * invT;
        feat[3201] = sy * invT;
        feat[3202] = sz * invT;
    }
}

// ---------------------------------------------------------------------------
// Kernel 2 (copy-kernel-shaped GEMV): one wave = one (row, 256-float chunk).
// 140000 wave-tasks = 35000 blocks x 256 thr. Per wave: ONE 1KB weight load,
// one L1-hit feature load, 4 FMAs, 6-shuffle reduce, one partial store.
// Max TLP (VGPR ~20, no LDS, no barriers) -> vmem queue never empties,
// mimicking the 6.3TB/s grid-stride copy pattern (R3-R8 were latency-bound
// at 21-35% occupancy with bursty per-wave loads).
// wid<50000: W1 (5 chunks/row); <100000: W2; else W3 (4 chunks/row).
// ---------------------------------------------------------------------------
__global__ __launch_bounds__(256)
void hdc_dot_kernel(const float* __restrict__ W1, const float* __restrict__ W2,
                    const float* __restrict__ W3, const float* __restrict__ feat,
                    float* __restrict__ partial) {
    const int wid = blockIdx.x * 4 + (threadIdx.x >> 6);   // 0..139999
    const int lane = threadIdx.x & 63;

    const float* __restrict__ Wm;
    int row, c, len, foff, slot;
    if (wid < 50000) {
        Wm = W1; row = wid / 5; c = wid - row * 5; len = L12; foff = 0; slot = c;
    } else if (wid < 100000) {
        const int u = wid - 50000;
        Wm = W2; row = u / 5; c = u - row * 5; len = L12; foff = 1200; slot = 5 + c;
    } else {
        const int u = wid - 100000;
        Wm = W3; row = u / 4; c = u - row * 4; len = L3; foff = 2400; slot = 10 + c;
    }

    const int k = c * 256 + lane * 4;
    float t = 0.f;
    if (k < len) {     // tail chunks: W1/W2 c=4 -> lanes 0..43; W3 c=3 -> 0..7
        const float4 w = *reinterpret_cast<const float4*>(Wm + (size_t)row * len + k);
        const float4 f = *reinterpret_cast<const float4*>(feat + foff + k);
        t = w.x * f.x + w.y * f.y + w.z * f.z + w.w * f.w;
    }
    #pragma unroll
    for (int off = 32; off; off >>= 1) t += __shfl_down(t, off, 64);
    if (lane == 0) partial[row * 16 + slot] = t;
}

// ---------------------------------------------------------------------------
// Kernel 3: sum partials + 4-way tanh epilogue. One thread per output row.
// ---------------------------------------------------------------------------
__global__ __launch_bounds__(256)
void hdc_tanh_kernel(const float* __restrict__ partial,
                     const float* __restrict__ b1, const float* __restrict__ b2,
                     const float* __restrict__ b3, const float* __restrict__ W4,
                     const float* __restrict__ b4, const float* __restrict__ feat,
                     float* __restrict__ out) {
    const int d = blockIdx.x * 256 + threadIdx.x;
    if (d >= D_OUT) return;
    const float* __restrict__ p = partial + d * 16;
    const float a1 = ((p[0] + p[1]) + (p[2] + p[3])) + p[4];
    const float a2 = ((p[5] + p[6]) + (p[7] + p[8])) + p[9];
    const float a3 = (p[10] + p[11]) + (p[12] + p[13]);
    const float e0 = feat[3200], e1 = feat[3201], e2 = feat[3202];
    const float hv1 = tanhf(a1 + b1[d]);
    const float hv2 = tanhf(a2 + b2[d]);
    const float hv3 = tanhf(a3 + b3[d]);
    const float hv4 = tanhf(W4[(size_t)d * 3 + 0] * e0 +
                            W4[(size_t)d * 3 + 1] * e1 +
                            W4[(size_t)d * 3 + 2] * e2 + b4[d]);
    out[d] = tanhf(hv1 * hv4 + hv2 + hv3);
}

// ---------------------------------------------------------------------------
// Fallback (R7 design, proven 43us) if ws is too small for partials.
// ---------------------------------------------------------------------------
__global__ __launch_bounds__(256)
void hdc_gemv_fallback(const float* __restrict__ W1, const float* __restrict__ b1,
                       const float* __restrict__ W2, const float* __restrict__ b2,
                       const float* __restrict__ W3, const float* __restrict__ b3,
                       const float* __restrict__ W4, const float* __restrict__ b4,
                       const float* __restrict__ feat, float* __restrict__ out) {
    __shared__ __align__(16) float g[3203];
    const int tid = threadIdx.x;
    const int wave = tid >> 6, lane = tid & 63;
    const int d = blockIdx.x * 4 + wave;
    const int c0 = lane * 4;

    const float* __restrict__ w1 = W1 + (size_t)d * L12;
    const float* __restrict__ w2 = W2 + (size_t)d * L12;
    const float* __restrict__ w3 = W3 + (size_t)d * L3;

    float4 r[12];
    #pragma unroll
    for (int i = 0; i < 12; ++i) {
        const int k = 256 * i + c0;
        const float* p;
        if (i < 4)       p = w1 + k;
        else if (i == 4) p = (k < L12) ? (w1 + k) : (w2 + (k - L12));
        else if (i < 9)  p = w2 + (k - L12);
        else if (i == 9) p = (k < 2400) ? (w2 + (k - L12)) : (w3 + (k - 2400));
        else             p = w3 + (k - 2400);
        r[i] = *reinterpret_cast<const float4*>(p);
    }
    const float2 rt = *reinterpret_cast<const float2*>(w3 + 672 + 2 * lane);

    {
        float4* g4 = reinterpret_cast<float4*>(g);
        const float4* feat4 = reinterpret_cast<const float4*>(feat);
        for (int i = tid; i < 800; i += 256) g4[i] = feat4[i];
        if (tid == 0) { g[3200] = feat[3200]; g[3201] = feat[3201]; g[3202] = feat[3202]; }
    }
    __syncthreads();

    float acc1 = 0.f, acc2 = 0.f, acc3 = 0.f;
    #pragma unroll
    for (int i = 0; i < 12; ++i) {
        const int k = 256 * i + c0;
        const float4 s = *reinterpret_cast<const float4*>(&g[k]);
        const float t = r[i].x * s.x + r[i].y * s.y + r[i].z * s.z + r[i].w * s.w;
        if (i < 4)       acc1 += t;
        else if (i == 4) { acc1 += (k < L12) ? t : 0.f; acc2 += (k < L12) ? 0.f : t; }
        else if (i < 9)  acc2 += t;
        else if (i == 9) { acc2 += (k < 2400) ? t : 0.f; acc3 += (k < 2400) ? 0.f : t; }
        else             acc3 += t;
    }
    {
        const int k = 3072 + 2 * lane;
        acc3 += rt.x * g[k] + rt.y * g[k + 1];
    }

    #pragma unroll
    for (int off = 32; off; off >>= 1) {
        acc1 += __shfl_down(acc1, off, 64);
        acc2 += __shfl_down(acc2, off, 64);
        acc3 += __shfl_down(acc3, off, 64);
    }

    if (lane == 0) {
        const float e0 = g[3200], e1 = g[3201], e2 = g[3202];
        const float hv1 = tanhf(acc1 + b1[d]);
        const float hv2 = tanhf(acc2 + b2[d]);
        const float hv3 = tanhf(acc3 + b3[d]);
        const float hv4 = tanhf(W4[(size_t)d * 3 + 0] * e0 +
                                W4[(size_t)d * 3 + 1] * e1 +
                                W4[(size_t)d * 3 + 2] * e2 + b4[d]);
        out[d] = tanhf(hv1 * hv4 + hv2 + hv3);
    }
}

extern "C" void kernel_launch(void* const* d_in, const int* in_sizes, int n_in,
                              void* d_out, int out_size, void* d_ws, size_t ws_size,
                              hipStream_t stream) {
    const float* input = (const float*)d_in[0];
    const float* W1 = (const float*)d_in[1];
    const float* b1 = (const float*)d_in[2];
    const float* W2 = (const float*)d_in[3];
    const float* b2 = (const float*)d_in[4];
    const float* W3 = (const float*)d_in[5];
    const float* b3 = (const float*)d_in[6];
    const float* W4 = (const float*)d_in[7];
    const float* b4 = (const float*)d_in[8];
    float* out = (float*)d_out;
    float* feat = (float*)d_ws;

    hdc_features_kernel<<<1, 512, 0, stream>>>(input, feat);

    if (ws_size >= WS_NEED) {
        float* partial = feat + PART_OFF;
        hdc_dot_kernel<<<35000, 256, 0, stream>>>(W1, W2, W3, feat, partial);
        hdc_tanh_kernel<<<(D_OUT + 255) / 256, 256, 0, stream>>>(
            partial, b1, b2, b3, W4, b4, feat, out);
    } else {
        hdc_gemv_fallback<<<D_OUT / 4, 256, 0, stream>>>(W1, b1, W2, b2, W3, b3,
                                                         W4, b4, feat, out);
    }
}